// Round 8
// baseline (786.783 us; speedup 1.0000x reference)
//
#include <hip/hip_runtime.h>
#include <math.h>

#define N_NODES 8192
#define NFEAT 512
#define NHID 512
#define NCLASS 8
#define RCAP 192     // max row degree; Binomial(8192,0.01): mean 82, std 9 -> 192 is ~12 sigma
#define KB_SPLIT 1536  // B operand: [hi | lo | hi] bf16
#define KA_SPLIT 1024  // A operand: [hi | lo] bf16 (chunk map re-reads hi)
#define CANDCAP 64     // score candidates within FILTER_MARGIN of row max (expected ~1.6)
#define FILTER_MARGIN 256.0f  // fp8 filter noise sigma ~34 -> z>6 for weight-significant drops

// ---------- bf16 split helpers ----------
__device__ inline ushort f2bf(float f) {
  uint32_t u = __float_as_uint(f);
  uint32_t r = u + 0x7fffu + ((u >> 16) & 1u);
  return (ushort)(r >> 16);
}
__device__ inline float bf2f(ushort h) { return __uint_as_float(((uint32_t)h) << 16); }

// ---------- fp8 e4m3 (h >= 0 post-relu: no sign bit needed) ----------
__device__ inline uint32_t f2e4m3(float a) {
  if (a < 0.015625f) return 0u;          // flush denormal range (|err| <= 2^-6, ~0.7 elems/row)
  if (a >= 448.f) return 0x7Eu;          // clamp (never for our data)
  uint32_t b = __float_as_uint(a);
  uint32_t r = b + 0x000FFFFFu + ((b >> 20) & 1u);  // RN-even to 3 mantissa bits
  return ((r >> 20) - 960u) & 0x7fu;     // ((E+127)<<3|m) - 120<<3
}
// decode: (code+960)<<20 re-biases exponent; code 0 -> 0
__device__ inline float dece4m3(uint32_t c) {
  return c ? __uint_as_float((c + 960u) << 20) : 0.f;
}
__device__ inline void dec4fma(uint32_t w, float4 g, float& s) {
  s = fmaf(dece4m3(w & 0xffu), g.x, s);
  s = fmaf(dece4m3((w >> 8) & 0xffu), g.y, s);
  s = fmaf(dece4m3((w >> 16) & 0xffu), g.z, s);
  s = fmaf(dece4m3(w >> 24), g.w, s);
}

// ---------------- adjacency: dense 0/1 -> ELL (single 256MB pass) ----------------
__global__ __launch_bounds__(256) void build_ell(const float* __restrict__ adj,
                                                 int* __restrict__ colidx,
                                                 int* __restrict__ deg) {
  int row = blockIdx.x;
  __shared__ int cnt;
  __shared__ int cols[RCAP];
  if (threadIdx.x == 0) cnt = 0;
  __syncthreads();
  const float4* arow = (const float4*)(adj + (size_t)row * N_NODES);
  for (int i = threadIdx.x; i < N_NODES / 4; i += 256) {
    float4 v = arow[i];
    int base = i * 4;
    if (v.x > 0.5f) { int p = atomicAdd(&cnt, 1); if (p < RCAP) cols[p] = base; }
    if (v.y > 0.5f) { int p = atomicAdd(&cnt, 1); if (p < RCAP) cols[p] = base + 1; }
    if (v.z > 0.5f) { int p = atomicAdd(&cnt, 1); if (p < RCAP) cols[p] = base + 2; }
    if (v.w > 0.5f) { int p = atomicAdd(&cnt, 1); if (p < RCAP) cols[p] = base + 3; }
  }
  __syncthreads();
  int d = cnt < RCAP ? cnt : RCAP;
  if (threadIdx.x == 0) deg[row] = d;
  for (int i = threadIdx.x; i < d; i += 256) colidx[(size_t)row * RCAP + i] = cols[i];
}

// ---------------- 512x512 transpose ----------------
__global__ void transpose512(const float* __restrict__ in, float* __restrict__ out) {
  __shared__ float tile[32][33];
  int x = blockIdx.x * 32 + threadIdx.x;
  int y0 = blockIdx.y * 32;
  for (int i = threadIdx.y; i < 32; i += 8)
    tile[i][threadIdx.x] = in[(size_t)(y0 + i) * 512 + x];
  __syncthreads();
  int xo = blockIdx.y * 32 + threadIdx.x;
  int yo0 = blockIdx.x * 32;
  for (int i = threadIdx.y; i < 32; i += 8)
    out[(size_t)(yo0 + i) * 512 + xo] = tile[threadIdx.x][i];
}

// ---------------- fp32 SGEMM (small 512^3: M = Qw@Kw^T) ----------------
__global__ __launch_bounds__(256) void sgemm64x128(const float* __restrict__ A,
                                                   const float* __restrict__ B,
                                                   float* __restrict__ C,
                                                   int M, int Nn, int K, int ldc) {
  __shared__ float As[16][68];
  __shared__ float Bs[16][132];
  const int tid = threadIdx.x;
  const int bm = blockIdx.y * 64, bn = blockIdx.x * 128;
  const int tx = tid & 15, ty = tid >> 4;
  const int arow = tid >> 2, acol = (tid & 3) << 2;
  const int brow = tid >> 4, bcol = (tid & 15) << 2;
  float acc[4][8];
#pragma unroll
  for (int i = 0; i < 4; ++i)
#pragma unroll
    for (int j = 0; j < 8; ++j) acc[i][j] = 0.f;
  const float* Ap = A + (size_t)(bm + arow) * K + acol;
  const float* Bp = B + (size_t)brow * Nn + bn + bcol;
  float4 av = *(const float4*)(Ap);
  float4 bv0 = *(const float4*)(Bp);
  float4 bv1 = *(const float4*)(Bp + 64);
  for (int k0 = 0; k0 < K; k0 += 16) {
    if (k0) __syncthreads();
    As[acol + 0][arow] = av.x;
    As[acol + 1][arow] = av.y;
    As[acol + 2][arow] = av.z;
    As[acol + 3][arow] = av.w;
    *(float4*)&Bs[brow][bcol] = bv0;
    *(float4*)&Bs[brow][bcol + 64] = bv1;
    __syncthreads();
    int kn = (k0 + 16 < K) ? k0 + 16 : 0;
    av = *(const float4*)(Ap + kn);
    bv0 = *(const float4*)(Bp + (size_t)kn * Nn);
    bv1 = *(const float4*)(Bp + (size_t)kn * Nn + 64);
#pragma unroll
    for (int kk = 0; kk < 16; ++kk) {
      float4 a = *(const float4*)&As[kk][ty << 2];
      float4 b0 = *(const float4*)&Bs[kk][tx << 2];
      float4 b1 = *(const float4*)&Bs[kk][(tx << 2) + 64];
      float ar[4] = {a.x, a.y, a.z, a.w};
      float br[8] = {b0.x, b0.y, b0.z, b0.w, b1.x, b1.y, b1.z, b1.w};
#pragma unroll
      for (int i = 0; i < 4; ++i)
#pragma unroll
        for (int j = 0; j < 8; ++j) acc[i][j] = fmaf(ar[i], br[j], acc[i][j]);
    }
  }
#pragma unroll
  for (int i = 0; i < 4; ++i) {
    int r = bm + (ty << 2) + i;
    *(float4*)(C + (size_t)r * ldc + bn + (tx << 2)) =
        make_float4(acc[i][0], acc[i][1], acc[i][2], acc[i][3]);
    *(float4*)(C + (size_t)r * ldc + bn + 64 + (tx << 2)) =
        make_float4(acc[i][4], acc[i][5], acc[i][6], acc[i][7]);
  }
}

// ---------------- split A [Mx512] fp32 -> [M x 1024] bf16 = [hi | lo] ----------------
__global__ __launch_bounds__(256) void split_a2(const float* __restrict__ A, ushort* __restrict__ As) {
  int idx = blockIdx.x * 256 + threadIdx.x;  // over M*128 float4s
  int m = idx >> 7, t = idx & 127;
  float4 v = ((const float4*)(A + (size_t)m * 512))[t];
  ushort4 hi, lo;
  hi.x = f2bf(v.x); hi.y = f2bf(v.y); hi.z = f2bf(v.z); hi.w = f2bf(v.w);
  lo.x = f2bf(v.x - bf2f(hi.x)); lo.y = f2bf(v.y - bf2f(hi.y));
  lo.z = f2bf(v.z - bf2f(hi.z)); lo.w = f2bf(v.w - bf2f(hi.w));
  ushort* row = As + (size_t)m * KA_SPLIT;
  ((ushort4*)row)[t] = hi;
  ((ushort4*)(row + 512))[t] = lo;
}

// ---------------- split+transpose B [512xNn] fp32 -> Bt [Nn x 1536] bf16 = [hi | lo | hi] ----------------
__global__ __launch_bounds__(256) void split_bt(const float* __restrict__ B, ushort* __restrict__ Bt, int Nn) {
  int idx = blockIdx.x * 256 + threadIdx.x;  // over Nn*384 ushort4s
  int n = idx / 384, t = idx % 384;
  int sec = t >> 7;  // 0:hi 1:lo 2:hi
  int k0 = (t & 127) << 2;
  ushort4 o;
  float f0 = B[(size_t)(k0 + 0) * Nn + n];
  float f1 = B[(size_t)(k0 + 1) * Nn + n];
  float f2 = B[(size_t)(k0 + 2) * Nn + n];
  float f3 = B[(size_t)(k0 + 3) * Nn + n];
  if (sec == 1) {
    o.x = f2bf(f0 - bf2f(f2bf(f0))); o.y = f2bf(f1 - bf2f(f2bf(f1)));
    o.z = f2bf(f2 - bf2f(f2bf(f2))); o.w = f2bf(f3 - bf2f(f2bf(f3)));
  } else {
    o.x = f2bf(f0); o.y = f2bf(f1); o.z = f2bf(f2); o.w = f2bf(f3);
  }
  ((ushort4*)(Bt + (size_t)n * KB_SPLIT))[t] = o;
}

// same, for Bcat = [Mmat | Vw] columns (Nn = 1024)
__global__ __launch_bounds__(256) void split_bt_cat(const float* __restrict__ Mm, const float* __restrict__ Vw,
                                                    ushort* __restrict__ Bt) {
  int idx = blockIdx.x * 256 + threadIdx.x;  // over 1024*384
  int n = idx / 384, t = idx % 384;
  const float* src = (n < 512) ? (Mm + n) : (Vw + (n - 512));
  int sec = t >> 7;
  int k0 = (t & 127) << 2;
  ushort4 o;
  float f0 = src[(size_t)(k0 + 0) * 512];
  float f1 = src[(size_t)(k0 + 1) * 512];
  float f2 = src[(size_t)(k0 + 2) * 512];
  float f3 = src[(size_t)(k0 + 3) * 512];
  if (sec == 1) {
    o.x = f2bf(f0 - bf2f(f2bf(f0))); o.y = f2bf(f1 - bf2f(f2bf(f1)));
    o.z = f2bf(f2 - bf2f(f2bf(f2))); o.w = f2bf(f3 - bf2f(f2bf(f3)));
  } else {
    o.x = f2bf(f0); o.y = f2bf(f1); o.z = f2bf(f2); o.w = f2bf(f3);
  }
  ((ushort4*)(Bt + (size_t)n * KB_SPLIT))[t] = o;
}

// bcat = [0 | Vb]; T = 0  (merged prep)
__global__ void prep_misc(const float* __restrict__ Vb, float* __restrict__ bcat,
                          float* __restrict__ T) {
  int i = blockIdx.x * 256 + threadIdx.x;
  if (i < 1024) bcat[i] = (i < 512) ? 0.f : Vb[i - 512];
  else if (i < 1536) T[i - 1024] = 0.f;
}

// ---------------- bf16x3 MFMA GEMM (128x128 tile): C = A @ Bt^T (+bias), fused colsum ----------------
using frag_ab = __attribute__((ext_vector_type(8))) short;
using frag_cd = __attribute__((ext_vector_type(4))) float;

__global__ __launch_bounds__(256) void mfma_gemm_bt(const ushort* __restrict__ A,
                                                    const ushort* __restrict__ Bt,
                                                    const float* __restrict__ bias,
                                                    float* __restrict__ C,
                                                    int ldc, float* __restrict__ Tsum) {
  __shared__ __align__(16) ushort Atile[128 * 64];
  __shared__ __align__(16) ushort Btile[128 * 64];
  const int tid = threadIdx.x;
  const int w = tid >> 6, lane = tid & 63;
  const int m0 = blockIdx.y * 128, n0 = blockIdx.x * 128;
  const int wm = (w >> 1) * 64, wn = (w & 1) * 64;
  const int q = lane >> 4, c16 = lane & 15;

  frag_cd acc[4][4];
#pragma unroll
  for (int i = 0; i < 4; ++i)
#pragma unroll
    for (int j = 0; j < 4; ++j) acc[i][j] = (frag_cd){0.f, 0.f, 0.f, 0.f};

  const int srow = (w << 3) + (lane >> 3);
  const int scolb = (lane & 7) << 4;
  const uint8_t* gA = (const uint8_t*)A + (size_t)(m0 + srow) * (KA_SPLIT * 2) + scolb;
  const uint8_t* gB = (const uint8_t*)Bt + (size_t)(n0 + srow) * (KB_SPLIT * 2) + scolb;

  for (int c = 0; c < 24; ++c) {
    const size_t kaB = (size_t)((c < 8 ? c : c - 8) * 128);
    const size_t kbB = (size_t)(c * 128);
#pragma unroll
    for (int r = 0; r < 4; ++r) {
      __builtin_amdgcn_global_load_lds(
          (const __attribute__((address_space(1))) uint32_t*)(gA + (size_t)(r * 32) * (KA_SPLIT * 2) + kaB),
          (__attribute__((address_space(3))) uint32_t*)((uint8_t*)Atile + r * 4096 + w * 1024), 16, 0, 0);
      __builtin_amdgcn_global_load_lds(
          (const __attribute__((address_space(1))) uint32_t*)(gB + (size_t)(r * 32) * (KB_SPLIT * 2) + kbB),
          (__attribute__((address_space(3))) uint32_t*)((uint8_t*)Btile + r * 4096 + w * 1024), 16, 0, 0);
    }
    __syncthreads();
#pragma unroll
    for (int kk = 0; kk < 2; ++kk) {
      frag_ab af[4], bf[4];
#pragma unroll
      for (int i = 0; i < 4; ++i) {
        af[i] = *(const frag_ab*)((const uint8_t*)Atile + (wm + i * 16 + c16) * 128 + kk * 64 + q * 16);
        bf[i] = *(const frag_ab*)((const uint8_t*)Btile + (wn + i * 16 + c16) * 128 + kk * 64 + q * 16);
      }
#pragma unroll
      for (int i = 0; i < 4; ++i)
#pragma unroll
        for (int j = 0; j < 4; ++j)
          acc[i][j] = __builtin_amdgcn_mfma_f32_16x16x32_bf16(af[i], bf[j], acc[i][j], 0, 0, 0);
    }
    __syncthreads();
  }
  // C/D layout: col = lane&15, row = (lane>>4)*4 + reg
#pragma unroll
  for (int j = 0; j < 4; ++j) {
    int col = n0 + wn + j * 16 + c16;
    float bv = bias ? bias[col] : 0.f;
    float csum = 0.f;
#pragma unroll
    for (int i = 0; i < 4; ++i) {
      int row = m0 + wm + i * 16 + q * 4;
#pragma unroll
      for (int r = 0; r < 4; ++r) {
        float v = acc[i][j][r] + bv;
        C[(size_t)(row + r) * ldc + col] = v;
        csum += v;
      }
    }
    if (Tsum && col >= 512) {  // fused T = colsum(Vh)
      csum += __shfl_xor(csum, 16, 64);
      csum += __shfl_xor(csum, 32, 64);
      if (q == 0) atomicAdd(&Tsum[col - 512], csum);
    }
  }
}

// ---------------- bf16x3 MFMA GEMM (64x128 tile): 512 blocks -> 2 waves/SIMD for N=512 GEMM ----------------
__global__ __launch_bounds__(256) void mfma_gemm_m64(const ushort* __restrict__ A,
                                                     const ushort* __restrict__ Bt,
                                                     float* __restrict__ C, int ldc) {
  __shared__ __align__(16) ushort Atile[64 * 64];
  __shared__ __align__(16) ushort Btile[128 * 64];
  const int tid = threadIdx.x;
  const int w = tid >> 6, lane = tid & 63;
  const int m0 = blockIdx.y * 64, n0 = blockIdx.x * 128;
  const int wn = w * 32;                 // 4 waves across N: each 64x32
  const int q = lane >> 4, c16 = lane & 15;

  frag_cd acc[4][2];
#pragma unroll
  for (int i = 0; i < 4; ++i)
#pragma unroll
    for (int j = 0; j < 2; ++j) acc[i][j] = (frag_cd){0.f, 0.f, 0.f, 0.f};

  const int srow = (w << 3) + (lane >> 3);
  const int scolb = (lane & 7) << 4;
  const uint8_t* gA = (const uint8_t*)A + (size_t)(m0 + srow) * (KA_SPLIT * 2) + scolb;
  const uint8_t* gB = (const uint8_t*)Bt + (size_t)(n0 + srow) * (KB_SPLIT * 2) + scolb;

  for (int c = 0; c < 24; ++c) {
    const size_t kaB = (size_t)((c < 8 ? c : c - 8) * 128);
    const size_t kbB = (size_t)(c * 128);
#pragma unroll
    for (int r = 0; r < 2; ++r)
      __builtin_amdgcn_global_load_lds(
          (const __attribute__((address_space(1))) uint32_t*)(gA + (size_t)(r * 32) * (KA_SPLIT * 2) + kaB),
          (__attribute__((address_space(3))) uint32_t*)((uint8_t*)Atile + r * 4096 + w * 1024), 16, 0, 0);
#pragma unroll
    for (int r = 0; r < 4; ++r)
      __builtin_amdgcn_global_load_lds(
          (const __attribute__((address_space(1))) uint32_t*)(gB + (size_t)(r * 32) * (KB_SPLIT * 2) + kbB),
          (__attribute__((address_space(3))) uint32_t*)((uint8_t*)Btile + r * 4096 + w * 1024), 16, 0, 0);
    __syncthreads();
#pragma unroll
    for (int kk = 0; kk < 2; ++kk) {
      frag_ab af[4], bf[2];
#pragma unroll
      for (int i = 0; i < 4; ++i)
        af[i] = *(const frag_ab*)((const uint8_t*)Atile + (i * 16 + c16) * 128 + kk * 64 + q * 16);
#pragma unroll
      for (int j = 0; j < 2; ++j)
        bf[j] = *(const frag_ab*)((const uint8_t*)Btile + (wn + j * 16 + c16) * 128 + kk * 64 + q * 16);
#pragma unroll
      for (int i = 0; i < 4; ++i)
#pragma unroll
        for (int j = 0; j < 2; ++j)
          acc[i][j] = __builtin_amdgcn_mfma_f32_16x16x32_bf16(af[i], bf[j], acc[i][j], 0, 0, 0);
    }
    __syncthreads();
  }
#pragma unroll
  for (int j = 0; j < 2; ++j) {
    int col = n0 + wn + j * 16 + c16;
#pragma unroll
    for (int i = 0; i < 4; ++i) {
      int row = m0 + i * 16 + q * 4;
#pragma unroll
      for (int r = 0; r < 4; ++r)
        C[(size_t)(row + r) * ldc + col] = acc[i][j][r];
    }
  }
}

// ---------------- rank-1 bias helpers: u = Qw@Kb, w = Kw@Qb, c = Qb.Kb ----------------
__global__ __launch_bounds__(64) void bias_prep(const float* __restrict__ Qw, const float* __restrict__ Kw,
                                                const float* __restrict__ Qb, const float* __restrict__ Kb,
                                                float* __restrict__ u, float* __restrict__ w,
                                                float* __restrict__ cbuf) {
  int k = blockIdx.x;
  int lane = threadIdx.x;
  if (k == NHID) {
    float s = 0.f;
    for (int j = lane; j < NHID; j += 64) s = fmaf(Qb[j], Kb[j], s);
#pragma unroll
    for (int o = 32; o > 0; o >>= 1) s += __shfl_down(s, o, 64);
    if (lane == 0) cbuf[0] = s;
    return;
  }
  float su = 0.f, sw = 0.f;
  for (int j = lane; j < NHID; j += 64) {
    su = fmaf(Qw[(size_t)k * NHID + j], Kb[j], su);
    sw = fmaf(Kw[(size_t)k * NHID + j], Qb[j], sw);
  }
#pragma unroll
  for (int o = 32; o > 0; o >>= 1) { su += __shfl_down(su, o, 64); sw += __shfl_down(sw, o, 64); }
  if (lane == 0) { u[k] = su; w[k] = sw; }
}

// ---------------- fused SpMM: h = relu(adj@xW + b1) + bf16 split + fp8 copy + a/b dots ----------------
__global__ __launch_bounds__(128) void spmm_fused(const float* __restrict__ xW,
                                                  const int* __restrict__ colidx,
                                                  const int* __restrict__ deg,
                                                  const float* __restrict__ b1,
                                                  const float* __restrict__ u, const float* __restrict__ w,
                                                  float* __restrict__ h, ushort* __restrict__ Hs,
                                                  uint32_t* __restrict__ H8,
                                                  float* __restrict__ a_vec, float* __restrict__ b_vec) {
  __shared__ int scols[RCAP];
  __shared__ float ra[2], rb[2];
  int row = blockIdx.x, t = threadIdx.x;
  int d = deg[row];
  for (int i = t; i < d; i += 128) scols[i] = colidx[(size_t)row * RCAP + i];
  __syncthreads();
  float4 acc = make_float4(0.f, 0.f, 0.f, 0.f);
  int e = 0;
  for (; e + 8 <= d; e += 8) {
    float4 v0 = ((const float4*)(xW + (size_t)scols[e + 0] * NHID))[t];
    float4 v1 = ((const float4*)(xW + (size_t)scols[e + 1] * NHID))[t];
    float4 v2 = ((const float4*)(xW + (size_t)scols[e + 2] * NHID))[t];
    float4 v3 = ((const float4*)(xW + (size_t)scols[e + 3] * NHID))[t];
    float4 v4 = ((const float4*)(xW + (size_t)scols[e + 4] * NHID))[t];
    float4 v5 = ((const float4*)(xW + (size_t)scols[e + 5] * NHID))[t];
    float4 v6 = ((const float4*)(xW + (size_t)scols[e + 6] * NHID))[t];
    float4 v7 = ((const float4*)(xW + (size_t)scols[e + 7] * NHID))[t];
    acc.x += ((v0.x + v1.x) + (v2.x + v3.x)) + ((v4.x + v5.x) + (v6.x + v7.x));
    acc.y += ((v0.y + v1.y) + (v2.y + v3.y)) + ((v4.y + v5.y) + (v6.y + v7.y));
    acc.z += ((v0.z + v1.z) + (v2.z + v3.z)) + ((v4.z + v5.z) + (v6.z + v7.z));
    acc.w += ((v0.w + v1.w) + (v2.w + v3.w)) + ((v4.w + v5.w) + (v6.w + v7.w));
  }
  for (; e < d; ++e) {
    float4 v = ((const float4*)(xW + (size_t)scols[e] * NHID))[t];
    acc.x += v.x; acc.y += v.y; acc.z += v.z; acc.w += v.w;
  }
  float4 bv = ((const float4*)b1)[t];
  float4 o = make_float4(fmaxf(acc.x + bv.x, 0.f), fmaxf(acc.y + bv.y, 0.f),
                         fmaxf(acc.z + bv.z, 0.f), fmaxf(acc.w + bv.w, 0.f));
  ((float4*)(h + (size_t)row * NHID))[t] = o;
  ushort4 hi, lo;
  hi.x = f2bf(o.x); hi.y = f2bf(o.y); hi.z = f2bf(o.z); hi.w = f2bf(o.w);
  lo.x = f2bf(o.x - bf2f(hi.x)); lo.y = f2bf(o.y - bf2f(hi.y));
  lo.z = f2bf(o.z - bf2f(hi.z)); lo.w = f2bf(o.w - bf2f(hi.w));
  ushort* hr = Hs + (size_t)row * KA_SPLIT;
  ((ushort4*)hr)[t] = hi;
  ((ushort4*)(hr + 512))[t] = lo;
  // fp8 copy for the score filter (elements 4t..4t+3 -> bytes 4t..4t+3)
  H8[(size_t)row * 128 + t] = f2e4m3(o.x) | (f2e4m3(o.y) << 8) | (f2e4m3(o.z) << 16) |
                              (f2e4m3(o.w) << 24);
  float4 uv = ((const float4*)u)[t], wv4 = ((const float4*)w)[t];
  float sa = fmaf(o.x, uv.x, fmaf(o.y, uv.y, fmaf(o.z, uv.z, o.w * uv.w)));
  float sb = fmaf(o.x, wv4.x, fmaf(o.y, wv4.y, fmaf(o.z, wv4.z, o.w * wv4.w)));
  int wv = t >> 6, lane = t & 63;
#pragma unroll
  for (int off = 32; off > 0; off >>= 1) { sa += __shfl_down(sa, off, 64); sb += __shfl_down(sb, off, 64); }
  if (lane == 0) { ra[wv] = sa; rb[wv] = sb; }
  __syncthreads();
  if (t == 0) { a_vec[row] = ra[0] + ra[1]; b_vec[row] = rb[0] + rb[1]; }
}

// ---------------- two-level score pass: fp8 filter -> fp32 rescore of candidates ----------------
// One wave per row (4 rows/block). Phase A: filter via fp8 h gather (512 B/row) against exact
// fp32 G in registers; noise sigma ~34 << margin 256. Phase B: exact fp32 rescore (~1.6/row),
// closed-form-background softmax, thresholded aggregate + background*T, LayerNorm.
__global__ __launch_bounds__(256) void score2_agg_ln(
    const float* __restrict__ G, int ldg, const float* __restrict__ h,
    const uint32_t* __restrict__ H8, const int* __restrict__ colidx, const int* __restrict__ deg,
    const float* __restrict__ a_vec, const float* __restrict__ b_vec,
    const float* __restrict__ cbuf, const float* __restrict__ Vh, int ldv,
    const float* __restrict__ T, const float* __restrict__ lng,
    const float* __restrict__ lnb, float* __restrict__ Xt) {
  __shared__ int scols[4][RCAP];
  __shared__ float sbv[4][RCAP];
  __shared__ float sv[4][RCAP];
  __shared__ int cand[4][CANDCAP];
  __shared__ int ccnt[4];
  int t = threadIdx.x, wv = t >> 6, lane = t & 63;
  int row = blockIdx.x * 4 + wv;
  int d = deg[row];
  int q = lane >> 4, u = lane & 15;
  if (lane == 0) ccnt[wv] = 0;
  // exact fp32 G row in registers: lane u holds G[32u .. 32u+31] (replicated across quarter-waves)
  float4 ga[8];
  const float4* Gr4 = (const float4*)(G + (size_t)row * ldg);
#pragma unroll
  for (int j = 0; j < 8; ++j) ga[j] = Gr4[u * 8 + j];
  for (int i = lane; i < d; i += 64) {
    int c = colidx[(size_t)row * RCAP + i];
    scols[wv][i] = c;
    sbv[wv][i] = b_vec[c];
  }
  __syncthreads();
  // ---- Phase A: fp8 filter scores (512 B gathers) ----
  for (int e0 = 0; e0 < d; e0 += 4) {
    int e = e0 + q;
    bool act = e < d;
    int col = scols[wv][act ? e : 0];
    const uint4* hr8 = (const uint4*)(H8 + (size_t)col * 128);
    uint4 p0 = hr8[2 * u], p1 = hr8[2 * u + 1];
    float s = 0.f;
    dec4fma(p0.x, ga[0], s); dec4fma(p0.y, ga[1], s);
    dec4fma(p0.z, ga[2], s); dec4fma(p0.w, ga[3], s);
    dec4fma(p1.x, ga[4], s); dec4fma(p1.y, ga[5], s);
    dec4fma(p1.z, ga[6], s); dec4fma(p1.w, ga[7], s);
    s += __shfl_down(s, 8, 16);
    s += __shfl_down(s, 4, 16);
    s += __shfl_down(s, 2, 16);
    s += __shfl_down(s, 1, 16);
    if (u == 0 && act) sv[wv][e] = s + sbv[wv][e];  // b_j affects ranking; a_i+c is row-const
  }
  __syncthreads();
  float fm = -1e30f;
  for (int i = lane; i < d; i += 64) fm = fmaxf(fm, sv[wv][i]);
#pragma unroll
  for (int o = 32; o > 0; o >>= 1) fm = fmaxf(fm, __shfl_xor(fm, o, 64));
  for (int i = lane; i < d; i += 64) {
    if (sv[wv][i] >= fm - FILTER_MARGIN) {
      int p = atomicAdd(&ccnt[wv], 1);
      if (p < CANDCAP) cand[wv][p] = i;
    }
  }
  __syncthreads();
  int nc = ccnt[wv];
  bool ovf = nc > CANDCAP;       // degenerate near-tie row: rescore ALL edges (rare, still exact)
  if (ovf) nc = d;
  float ai = a_vec[row] + cbuf[0];
  // ---- Phase B: exact fp32 rescore of candidates ----
  for (int c0 = 0; c0 < nc; c0 += 4) {
    int idx = c0 + q;
    bool act = idx < nc;
    int e = act ? (ovf ? idx : cand[wv][idx]) : 0;
    int col = scols[wv][e];
    const float4* hr = (const float4*)(h + (size_t)col * NHID);
    float s_a = 0.f, s_b = 0.f;
#pragma unroll
    for (int j = 0; j < 8; j += 2) {
      float4 h0 = hr[u * 8 + j], h1 = hr[u * 8 + j + 1];
      float4 g0 = ga[j], g1 = ga[j + 1];
      s_a = fmaf(h0.x, g0.x, s_a); s_a = fmaf(h0.y, g0.y, s_a);
      s_a = fmaf(h0.z, g0.z, s_a); s_a = fmaf(h0.w, g0.w, s_a);
      s_b = fmaf(h1.x, g1.x, s_b); s_b = fmaf(h1.y, g1.y, s_b);
      s_b = fmaf(h1.z, g1.z, s_b); s_b = fmaf(h1.w, g1.w, s_b);
    }
    float s = s_a + s_b;
    s += __shfl_down(s, 8, 16);
    s += __shfl_down(s, 4, 16);
    s += __shfl_down(s, 2, 16);
    s += __shfl_down(s, 1, 16);
    if (u == 0 && act) sv[wv][e] = s + ai + sbv[wv][e];  // exact score
  }
  __syncthreads();
  // softmax over candidates + implicit background zeros
  float m = 0.f;
  for (int i = lane; i < nc; i += 64) {
    int e = ovf ? i : cand[wv][i];
    m = fmaxf(m, sv[wv][e]);
  }
#pragma unroll
  for (int o = 32; o > 0; o >>= 1) m = fmaxf(m, __shfl_xor(m, o, 64));
  float ssum = 0.f;
  for (int i = lane; i < nc; i += 64) {
    int e = ovf ? i : cand[wv][i];
    float ex = expf(sv[wv][e] - m);
    sv[wv][e] = ex;
    ssum += ex;
  }
#pragma unroll
  for (int o = 32; o > 0; o >>= 1) ssum += __shfl_xor(ssum, o, 64);
  float em = expf(-m);
  float inv = 1.f / (ssum + (float)(N_NODES - d) * em);
  float ci = em * inv;
  __syncthreads();
  // aggregate candidate Vh rows (weight > 1e-12) + background*T, then LayerNorm
  float4 a0 = make_float4(0.f, 0.f, 0.f, 0.f), a1 = a0;
  for (int i = 0; i < nc; ++i) {
    int e = ovf ? i : cand[wv][i];
    float we = sv[wv][e] * inv;
    if (we > 1e-12f) {
      const float4* vr = (const float4*)(Vh + (size_t)scols[wv][e] * ldv);
      float4 v0 = vr[lane * 2], v1 = vr[lane * 2 + 1];
      a0.x = fmaf(we, v0.x, a0.x); a0.y = fmaf(we, v0.y, a0.y);
      a0.z = fmaf(we, v0.z, a0.z); a0.w = fmaf(we, v0.w, a0.w);
      a1.x = fmaf(we, v1.x, a1.x); a1.y = fmaf(we, v1.y, a1.y);
      a1.z = fmaf(we, v1.z, a1.z); a1.w = fmaf(we, v1.w, a1.w);
    }
  }
  float4 t0 = ((const float4*)T)[lane * 2], t1 = ((const float4*)T)[lane * 2 + 1];
  a0.x = fmaf(ci, t0.x, a0.x); a0.y = fmaf(ci, t0.y, a0.y);
  a0.z = fmaf(ci, t0.z, a0.z); a0.w = fmaf(ci, t0.w, a0.w);
  a1.x = fmaf(ci, t1.x, a1.x); a1.y = fmaf(ci, t1.y, a1.y);
  a1.z = fmaf(ci, t1.z, a1.z); a1.w = fmaf(ci, t1.w, a1.w);
  float s1 = ((a0.x + a0.y) + (a0.z + a0.w)) + ((a1.x + a1.y) + (a1.z + a1.w));
  float s2 = ((a0.x * a0.x + a0.y * a0.y) + (a0.z * a0.z + a0.w * a0.w)) +
             ((a1.x * a1.x + a1.y * a1.y) + (a1.z * a1.z + a1.w * a1.w));
#pragma unroll
  for (int o = 32; o > 0; o >>= 1) { s1 += __shfl_xor(s1, o, 64); s2 += __shfl_xor(s2, o, 64); }
  float mu = s1 * (1.f / NHID);
  float var = s2 * (1.f / NHID) - mu * mu;
  float rstd = rsqrtf(var + 1e-5f);
  float4 g0 = ((const float4*)lng)[lane * 2], g1 = ((const float4*)lng)[lane * 2 + 1];
  float4 b0 = ((const float4*)lnb)[lane * 2], b1 = ((const float4*)lnb)[lane * 2 + 1];
  float4 o0, o1;
  o0.x = (a0.x - mu) * rstd * g0.x + b0.x;
  o0.y = (a0.y - mu) * rstd * g0.y + b0.y;
  o0.z = (a0.z - mu) * rstd * g0.z + b0.z;
  o0.w = (a0.w - mu) * rstd * g0.w + b0.w;
  o1.x = (a1.x - mu) * rstd * g1.x + b1.x;
  o1.y = (a1.y - mu) * rstd * g1.y + b1.y;
  o1.z = (a1.z - mu) * rstd * g1.z + b1.z;
  o1.w = (a1.w - mu) * rstd * g1.w + b1.w;
  float4* xr = (float4*)(Xt + (size_t)row * NHID);
  xr[lane * 2] = o0;
  xr[lane * 2 + 1] = o1;
}

// ---------------- Y = Xt @ W2 (512 -> 8), one wave per row ----------------
__global__ __launch_bounds__(256) void xt_w2(const float* __restrict__ Xt, const float* __restrict__ W2,
                                             float* __restrict__ Y) {
  __shared__ float w2s[NHID * NCLASS];
  int t = threadIdx.x;
  for (int i = t; i < NHID * NCLASS; i += 256) w2s[i] = W2[i];
  __syncthreads();
  int wv = t >> 6, lane = t & 63;
  int row = blockIdx.x * 4 + wv;
  const float4* xr = (const float4*)(Xt + (size_t)row * NHID);
  float4 x0 = xr[lane * 2], x1 = xr[lane * 2 + 1];
  float xv[8] = {x0.x, x0.y, x0.z, x0.w, x1.x, x1.y, x1.z, x1.w};
  float acc[NCLASS];
#pragma unroll
  for (int c = 0; c < NCLASS; ++c) acc[c] = 0.f;
#pragma unroll
  for (int kk = 0; kk < 8; ++kk) {
    int k = lane * 8 + kk;
#pragma unroll
    for (int c = 0; c < NCLASS; ++c) acc[c] = fmaf(xv[kk], w2s[k * NCLASS + c], acc[c]);
  }
#pragma unroll
  for (int c = 0; c < NCLASS; ++c)
#pragma unroll
    for (int o = 32; o > 0; o >>= 1) acc[c] += __shfl_down(acc[c], o, 64);
  if (lane == 0) {
    *(float4*)(Y + (size_t)row * NCLASS) = make_float4(acc[0], acc[1], acc[2], acc[3]);
    *(float4*)(Y + (size_t)row * NCLASS + 4) = make_float4(acc[4], acc[5], acc[6], acc[7]);
  }
}

// ---------------- z = adj @ Y + b2, softmax over 8 classes ----------------
__global__ __launch_bounds__(256) void final_spmm_softmax(const float* __restrict__ Y,
                                                          const int* __restrict__ colidx,
                                                          const int* __restrict__ deg,
                                                          const float* __restrict__ b2,
                                                          float* __restrict__ out) {
  int t = threadIdx.x;
  int wv = t >> 6, lane = t & 63;
  int row = blockIdx.x * 4 + wv;
  int d = deg[row];
  const int* cols = colidx + (size_t)row * RCAP;
  float acc[8];
#pragma unroll
  for (int c = 0; c < 8; ++c) acc[c] = 0.f;
  for (int e = lane; e < d; e += 64) {
    int col = cols[e];
    const float4* yr = (const float4*)(Y + (size_t)col * 8);
    float4 y0 = yr[0], y1 = yr[1];
    acc[0] += y0.x; acc[1] += y0.y; acc[2] += y0.z; acc[3] += y0.w;
    acc[4] += y1.x; acc[5] += y1.y; acc[6] += y1.z; acc[7] += y1.w;
  }
#pragma unroll
  for (int c = 0; c < 8; ++c)
#pragma unroll
    for (int o = 32; o > 0; o >>= 1) acc[c] += __shfl_down(acc[c], o, 64);
  if (lane == 0) {
    float z[8];
    float m = -1e30f;
#pragma unroll
    for (int c = 0; c < 8; ++c) { z[c] = acc[c] + b2[c]; m = fmaxf(m, z[c]); }
    float s = 0.f;
#pragma unroll
    for (int c = 0; c < 8; ++c) { z[c] = expf(z[c] - m); s += z[c]; }
    float inv = 1.f / s;
    *(float4*)(out + (size_t)row * 8) = make_float4(z[0] * inv, z[1] * inv, z[2] * inv, z[3] * inv);
    *(float4*)(out + (size_t)row * 8 + 4) = make_float4(z[4] * inv, z[5] * inv, z[6] * inv, z[7] * inv);
  }
}

extern "C" void kernel_launch(void* const* d_in, const int* in_sizes, int n_in,
                              void* d_out, int out_size, void* d_ws, size_t ws_size,
                              hipStream_t stream) {
  const float* adj = (const float*)d_in[0];
  const float* x = (const float*)d_in[1];
  const float* W1 = (const float*)d_in[2];
  const float* b1 = (const float*)d_in[3];
  const float* Qw = (const float*)d_in[4];
  const float* Qb = (const float*)d_in[5];
  const float* Kw = (const float*)d_in[6];
  const float* Kb = (const float*)d_in[7];
  const float* Vw = (const float*)d_in[8];
  const float* Vb = (const float*)d_in[9];
  const float* ln_g = (const float*)d_in[10];
  const float* ln_b = (const float*)d_in[11];
  const float* W2 = (const float*)d_in[12];
  const float* b2 = (const float*)d_in[13];
  float* out = (float*)d_out;

  char* ws = (char*)d_ws;
  size_t off = 0;
  auto alloc = [&](size_t bytes) -> void* {
    void* p = ws + off;
    off = (off + bytes + 255) & ~(size_t)255;
    return p;
  };
  int* colidx = (int*)alloc((size_t)N_NODES * RCAP * 4);
  int* deg = (int*)alloc((size_t)N_NODES * 4);
  float* bufA = (float*)alloc((size_t)N_NODES * NHID * 4);     // xW, then Xt
  float* bufB = (float*)alloc((size_t)N_NODES * NHID * 4);     // h
  float* GVh = (float*)alloc((size_t)N_NODES * 1024 * 4);      // [G | Vh], stride 1024
  ushort* Xs = (ushort*)alloc((size_t)N_NODES * KA_SPLIT * 2); // split x [hi|lo]
  ushort* Hs = (ushort*)alloc((size_t)N_NODES * KA_SPLIT * 2); // split h [hi|lo]
  uint32_t* H8 = (uint32_t*)alloc((size_t)N_NODES * 512);      // fp8 e4m3 copy of h
  ushort* W1ts = (ushort*)alloc((size_t)512 * KB_SPLIT * 2);   // split W1^T [hi|lo|hi]
  ushort* Bcts = (ushort*)alloc((size_t)1024 * KB_SPLIT * 2);  // split [M|Vw]^T
  float* KwT = (float*)alloc((size_t)512 * 512 * 4);
  float* Mmat = (float*)alloc((size_t)512 * 512 * 4);
  float* bcat = (float*)alloc((size_t)1024 * 4);
  float* a_vec = (float*)alloc((size_t)N_NODES * 4);
  float* b_vec = (float*)alloc((size_t)N_NODES * 4);
  float* u_vec = (float*)alloc((size_t)NHID * 4);
  float* w_vec = (float*)alloc((size_t)NHID * 4);
  float* cbuf = (float*)alloc(256);
  float* T = (float*)alloc((size_t)NHID * 4);
  float* Y = (float*)alloc((size_t)N_NODES * NCLASS * 4);
  (void)in_sizes; (void)n_in; (void)out_size; (void)ws_size;

  // 1) sparse structure from dense adj
  build_ell<<<N_NODES, 256, 0, stream>>>(adj, colidx, deg);
  // 2) M = Qw@Kw^T (fp32, small); rank-1 bias terms
  transpose512<<<dim3(16, 16), dim3(32, 8), 0, stream>>>(Kw, KwT);
  bias_prep<<<NHID + 1, 64, 0, stream>>>(Qw, Kw, Qb, Kb, u_vec, w_vec, cbuf);
  sgemm64x128<<<dim3(4, 8), 256, 0, stream>>>(Qw, KwT, Mmat, 512, 512, 512, 512);
  // 3) splits; xW = x@W1 via bf16x3 MFMA (64x128 tile -> 512 blocks, 2 waves/SIMD)
  split_a2<<<(N_NODES * 128) / 256, 256, 0, stream>>>(x, Xs);
  split_bt<<<(512 * 384) / 256, 256, 0, stream>>>(W1, W1ts, 512);
  mfma_gemm_m64<<<dim3(4, 128), 256, 0, stream>>>(Xs, W1ts, bufA, 512);
  // 4) h = relu(adj@xW + b1): fused gather + bf16 split + fp8 copy + a/b vectors
  spmm_fused<<<N_NODES, 128, 0, stream>>>(bufA, colidx, deg, b1, u_vec, w_vec, bufB, Hs, H8,
                                          a_vec, b_vec);
  // 5) [G | Vh] = h @ [M | Vw] (+[0|Vb]) via MFMA, fused T = colsum(Vh)
  split_bt_cat<<<(1024 * 384) / 256, 256, 0, stream>>>(Mmat, Vw, Bcts);
  prep_misc<<<6, 256, 0, stream>>>(Vb, bcat, T);
  mfma_gemm_bt<<<dim3(8, 64), 256, 0, stream>>>(Hs, Bcts, bcat, GVh, 1024, T);
  // 6) two-level scores (fp8 filter + fp32 rescore) + softmax + aggregate + LN -> Xt (bufA)
  score2_agg_ln<<<N_NODES / 4, 256, 0, stream>>>(GVh, 1024, bufB, H8, colidx, deg, a_vec, b_vec,
                                                 cbuf, GVh + 512, 1024, T, ln_g, ln_b, bufA);
  // 7) Y = Xt @ W2 ; z = adj @ Y + b2 ; softmax
  xt_w2<<<N_NODES / 4, 256, 0, stream>>>(bufA, W2, Y);
  final_spmm_softmax<<<N_NODES / 4, 256, 0, stream>>>(Y, colidx, deg, b2, out);
}

// Round 10
// 766.321 us; speedup vs baseline: 1.0267x; 1.0267x over previous
//
#include <hip/hip_runtime.h>
#include <math.h>

#define N_NODES 8192
#define NFEAT 512
#define NHID 512
#define NCLASS 8
#define RCAP 192     // max row degree; Binomial(8192,0.01): mean 82, std 9 -> 192 is ~12 sigma
#define KB_SPLIT 1536  // B operand: [hi | lo | hi] bf16
#define KA_SPLIT 1024  // A operand: [hi | lo] bf16 (chunk map re-reads hi)
#define CANDCAP 64     // score candidates within FILTER_MARGIN of row max (expected ~1.1)
#define FILTER_MARGIN 96.0f  // >= worst-case bf16-h filter error (~41) + 28 (1e-12 cutoff) + slack

// ---------- bf16 split helpers ----------
__device__ inline ushort f2bf(float f) {
  uint32_t u = __float_as_uint(f);
  uint32_t r = u + 0x7fffu + ((u >> 16) & 1u);
  return (ushort)(r >> 16);
}
__device__ inline float bf2f(ushort h) { return __uint_as_float(((uint32_t)h) << 16); }

// ---------------- adjacency: dense 0/1 -> ELL (single 256MB pass) ----------------
__global__ __launch_bounds__(256) void build_ell(const float* __restrict__ adj,
                                                 int* __restrict__ colidx,
                                                 int* __restrict__ deg) {
  int row = blockIdx.x;
  __shared__ int cnt;
  __shared__ int cols[RCAP];
  if (threadIdx.x == 0) cnt = 0;
  __syncthreads();
  const float4* arow = (const float4*)(adj + (size_t)row * N_NODES);
  for (int i = threadIdx.x; i < N_NODES / 4; i += 256) {
    float4 v = arow[i];
    int base = i * 4;
    if (v.x > 0.5f) { int p = atomicAdd(&cnt, 1); if (p < RCAP) cols[p] = base; }
    if (v.y > 0.5f) { int p = atomicAdd(&cnt, 1); if (p < RCAP) cols[p] = base + 1; }
    if (v.z > 0.5f) { int p = atomicAdd(&cnt, 1); if (p < RCAP) cols[p] = base + 2; }
    if (v.w > 0.5f) { int p = atomicAdd(&cnt, 1); if (p < RCAP) cols[p] = base + 3; }
  }
  __syncthreads();
  int d = cnt < RCAP ? cnt : RCAP;
  if (threadIdx.x == 0) deg[row] = d;
  for (int i = threadIdx.x; i < d; i += 256) colidx[(size_t)row * RCAP + i] = cols[i];
}

// ---------------- 512x512 transpose ----------------
__global__ void transpose512(const float* __restrict__ in, float* __restrict__ out) {
  __shared__ float tile[32][33];
  int x = blockIdx.x * 32 + threadIdx.x;
  int y0 = blockIdx.y * 32;
  for (int i = threadIdx.y; i < 32; i += 8)
    tile[i][threadIdx.x] = in[(size_t)(y0 + i) * 512 + x];
  __syncthreads();
  int xo = blockIdx.y * 32 + threadIdx.x;
  int yo0 = blockIdx.x * 32;
  for (int i = threadIdx.y; i < 32; i += 8)
    out[(size_t)(yo0 + i) * 512 + xo] = tile[threadIdx.x][i];
}

// ---------------- fp32 SGEMM (small 512^3: M = Qw@Kw^T) ----------------
__global__ __launch_bounds__(256) void sgemm64x128(const float* __restrict__ A,
                                                   const float* __restrict__ B,
                                                   float* __restrict__ C,
                                                   int M, int Nn, int K, int ldc) {
  __shared__ float As[16][68];
  __shared__ float Bs[16][132];
  const int tid = threadIdx.x;
  const int bm = blockIdx.y * 64, bn = blockIdx.x * 128;
  const int tx = tid & 15, ty = tid >> 4;
  const int arow = tid >> 2, acol = (tid & 3) << 2;
  const int brow = tid >> 4, bcol = (tid & 15) << 2;
  float acc[4][8];
#pragma unroll
  for (int i = 0; i < 4; ++i)
#pragma unroll
    for (int j = 0; j < 8; ++j) acc[i][j] = 0.f;
  const float* Ap = A + (size_t)(bm + arow) * K + acol;
  const float* Bp = B + (size_t)brow * Nn + bn + bcol;
  float4 av = *(const float4*)(Ap);
  float4 bv0 = *(const float4*)(Bp);
  float4 bv1 = *(const float4*)(Bp + 64);
  for (int k0 = 0; k0 < K; k0 += 16) {
    if (k0) __syncthreads();
    As[acol + 0][arow] = av.x;
    As[acol + 1][arow] = av.y;
    As[acol + 2][arow] = av.z;
    As[acol + 3][arow] = av.w;
    *(float4*)&Bs[brow][bcol] = bv0;
    *(float4*)&Bs[brow][bcol + 64] = bv1;
    __syncthreads();
    int kn = (k0 + 16 < K) ? k0 + 16 : 0;
    av = *(const float4*)(Ap + kn);
    bv0 = *(const float4*)(Bp + (size_t)kn * Nn);
    bv1 = *(const float4*)(Bp + (size_t)kn * Nn + 64);
#pragma unroll
    for (int kk = 0; kk < 16; ++kk) {
      float4 a = *(const float4*)&As[kk][ty << 2];
      float4 b0 = *(const float4*)&Bs[kk][tx << 2];
      float4 b1 = *(const float4*)&Bs[kk][(tx << 2) + 64];
      float ar[4] = {a.x, a.y, a.z, a.w};
      float br[8] = {b0.x, b0.y, b0.z, b0.w, b1.x, b1.y, b1.z, b1.w};
#pragma unroll
      for (int i = 0; i < 4; ++i)
#pragma unroll
        for (int j = 0; j < 8; ++j) acc[i][j] = fmaf(ar[i], br[j], acc[i][j]);
    }
  }
#pragma unroll
  for (int i = 0; i < 4; ++i) {
    int r = bm + (ty << 2) + i;
    *(float4*)(C + (size_t)r * ldc + bn + (tx << 2)) =
        make_float4(acc[i][0], acc[i][1], acc[i][2], acc[i][3]);
    *(float4*)(C + (size_t)r * ldc + bn + 64 + (tx << 2)) =
        make_float4(acc[i][4], acc[i][5], acc[i][6], acc[i][7]);
  }
}

// ---------------- split A [Mx512] fp32 -> [M x 1024] bf16 = [hi | lo] ----------------
__global__ __launch_bounds__(256) void split_a2(const float* __restrict__ A, ushort* __restrict__ As) {
  int idx = blockIdx.x * 256 + threadIdx.x;  // over M*128 float4s
  int m = idx >> 7, t = idx & 127;
  float4 v = ((const float4*)(A + (size_t)m * 512))[t];
  ushort4 hi, lo;
  hi.x = f2bf(v.x); hi.y = f2bf(v.y); hi.z = f2bf(v.z); hi.w = f2bf(v.w);
  lo.x = f2bf(v.x - bf2f(hi.x)); lo.y = f2bf(v.y - bf2f(hi.y));
  lo.z = f2bf(v.z - bf2f(hi.z)); lo.w = f2bf(v.w - bf2f(hi.w));
  ushort* row = As + (size_t)m * KA_SPLIT;
  ((ushort4*)row)[t] = hi;
  ((ushort4*)(row + 512))[t] = lo;
}

// ---------------- split+transpose B [512xNn] fp32 -> Bt [Nn x 1536] bf16 = [hi | lo | hi] ----------------
__global__ __launch_bounds__(256) void split_bt(const float* __restrict__ B, ushort* __restrict__ Bt, int Nn) {
  int idx = blockIdx.x * 256 + threadIdx.x;  // over Nn*384 ushort4s
  int n = idx / 384, t = idx % 384;
  int sec = t >> 7;  // 0:hi 1:lo 2:hi
  int k0 = (t & 127) << 2;
  ushort4 o;
  float f0 = B[(size_t)(k0 + 0) * Nn + n];
  float f1 = B[(size_t)(k0 + 1) * Nn + n];
  float f2 = B[(size_t)(k0 + 2) * Nn + n];
  float f3 = B[(size_t)(k0 + 3) * Nn + n];
  if (sec == 1) {
    o.x = f2bf(f0 - bf2f(f2bf(f0))); o.y = f2bf(f1 - bf2f(f2bf(f1)));
    o.z = f2bf(f2 - bf2f(f2bf(f2))); o.w = f2bf(f3 - bf2f(f2bf(f3)));
  } else {
    o.x = f2bf(f0); o.y = f2bf(f1); o.z = f2bf(f2); o.w = f2bf(f3);
  }
  ((ushort4*)(Bt + (size_t)n * KB_SPLIT))[t] = o;
}

// same, for Bcat = [Mmat | Vw] columns (Nn = 1024)
__global__ __launch_bounds__(256) void split_bt_cat(const float* __restrict__ Mm, const float* __restrict__ Vw,
                                                    ushort* __restrict__ Bt) {
  int idx = blockIdx.x * 256 + threadIdx.x;  // over 1024*384
  int n = idx / 384, t = idx % 384;
  const float* src = (n < 512) ? (Mm + n) : (Vw + (n - 512));
  int sec = t >> 7;
  int k0 = (t & 127) << 2;
  ushort4 o;
  float f0 = src[(size_t)(k0 + 0) * 512];
  float f1 = src[(size_t)(k0 + 1) * 512];
  float f2 = src[(size_t)(k0 + 2) * 512];
  float f3 = src[(size_t)(k0 + 3) * 512];
  if (sec == 1) {
    o.x = f2bf(f0 - bf2f(f2bf(f0))); o.y = f2bf(f1 - bf2f(f2bf(f1)));
    o.z = f2bf(f2 - bf2f(f2bf(f2))); o.w = f2bf(f3 - bf2f(f2bf(f3)));
  } else {
    o.x = f2bf(f0); o.y = f2bf(f1); o.z = f2bf(f2); o.w = f2bf(f3);
  }
  ((ushort4*)(Bt + (size_t)n * KB_SPLIT))[t] = o;
}

// bcat = [0 | Vb]; T = 0  (merged prep — validated in R8)
__global__ void prep_misc(const float* __restrict__ Vb, float* __restrict__ bcat,
                          float* __restrict__ T) {
  int i = blockIdx.x * 256 + threadIdx.x;
  if (i < 1024) bcat[i] = (i < 512) ? 0.f : Vb[i - 512];
  else if (i < 1536) T[i - 1024] = 0.f;
}

// ---------------- bf16x3 MFMA GEMM: C = A[hi|lo,K=1024] @ Bt[hi|lo|hi,K=1536]^T (+bias) ----------------
using frag_ab = __attribute__((ext_vector_type(8))) short;
using frag_cd = __attribute__((ext_vector_type(4))) float;

__global__ __launch_bounds__(256) void mfma_gemm_bt(const ushort* __restrict__ A,
                                                    const ushort* __restrict__ Bt,
                                                    const float* __restrict__ bias,
                                                    float* __restrict__ C,
                                                    int ldc, float* __restrict__ Tsum) {
  __shared__ __align__(16) ushort Atile[128 * 64];
  __shared__ __align__(16) ushort Btile[128 * 64];
  const int tid = threadIdx.x;
  const int w = tid >> 6, lane = tid & 63;
  const int m0 = blockIdx.y * 128, n0 = blockIdx.x * 128;
  const int wm = (w >> 1) * 64, wn = (w & 1) * 64;
  const int q = lane >> 4, c16 = lane & 15;

  frag_cd acc[4][4];
#pragma unroll
  for (int i = 0; i < 4; ++i)
#pragma unroll
    for (int j = 0; j < 4; ++j) acc[i][j] = (frag_cd){0.f, 0.f, 0.f, 0.f};

  const int srow = (w << 3) + (lane >> 3);
  const int scolb = (lane & 7) << 4;
  const uint8_t* gA = (const uint8_t*)A + (size_t)(m0 + srow) * (KA_SPLIT * 2) + scolb;
  const uint8_t* gB = (const uint8_t*)Bt + (size_t)(n0 + srow) * (KB_SPLIT * 2) + scolb;

  for (int c = 0; c < 24; ++c) {
    const size_t kaB = (size_t)((c < 8 ? c : c - 8) * 128);
    const size_t kbB = (size_t)(c * 128);
#pragma unroll
    for (int r = 0; r < 4; ++r) {
      __builtin_amdgcn_global_load_lds(
          (const __attribute__((address_space(1))) uint32_t*)(gA + (size_t)(r * 32) * (KA_SPLIT * 2) + kaB),
          (__attribute__((address_space(3))) uint32_t*)((uint8_t*)Atile + r * 4096 + w * 1024), 16, 0, 0);
      __builtin_amdgcn_global_load_lds(
          (const __attribute__((address_space(1))) uint32_t*)(gB + (size_t)(r * 32) * (KB_SPLIT * 2) + kbB),
          (__attribute__((address_space(3))) uint32_t*)((uint8_t*)Btile + r * 4096 + w * 1024), 16, 0, 0);
    }
    __syncthreads();
#pragma unroll
    for (int kk = 0; kk < 2; ++kk) {
      frag_ab af[4], bf[4];
#pragma unroll
      for (int i = 0; i < 4; ++i) {
        af[i] = *(const frag_ab*)((const uint8_t*)Atile + (wm + i * 16 + c16) * 128 + kk * 64 + q * 16);
        bf[i] = *(const frag_ab*)((const uint8_t*)Btile + (wn + i * 16 + c16) * 128 + kk * 64 + q * 16);
      }
#pragma unroll
      for (int i = 0; i < 4; ++i)
#pragma unroll
        for (int j = 0; j < 4; ++j)
          acc[i][j] = __builtin_amdgcn_mfma_f32_16x16x32_bf16(af[i], bf[j], acc[i][j], 0, 0, 0);
    }
    __syncthreads();
  }
  // C/D layout: col = lane&15, row = (lane>>4)*4 + reg
#pragma unroll
  for (int j = 0; j < 4; ++j) {
    int col = n0 + wn + j * 16 + c16;
    float bv = bias ? bias[col] : 0.f;
    float csum = 0.f;
#pragma unroll
    for (int i = 0; i < 4; ++i) {
      int row = m0 + wm + i * 16 + q * 4;
#pragma unroll
      for (int r = 0; r < 4; ++r) {
        float v = acc[i][j][r] + bv;
        C[(size_t)(row + r) * ldc + col] = v;
        csum += v;
      }
    }
    if (Tsum && col >= 512) {  // fused T = colsum(Vh)
      csum += __shfl_xor(csum, 16, 64);
      csum += __shfl_xor(csum, 32, 64);
      if (q == 0) atomicAdd(&Tsum[col - 512], csum);
    }
  }
}

// ---------------- rank-1 bias helpers: u = Qw@Kb, w = Kw@Qb, c = Qb.Kb ----------------
__global__ __launch_bounds__(64) void bias_prep(const float* __restrict__ Qw, const float* __restrict__ Kw,
                                                const float* __restrict__ Qb, const float* __restrict__ Kb,
                                                float* __restrict__ u, float* __restrict__ w,
                                                float* __restrict__ cbuf) {
  int k = blockIdx.x;
  int lane = threadIdx.x;
  if (k == NHID) {
    float s = 0.f;
    for (int j = lane; j < NHID; j += 64) s = fmaf(Qb[j], Kb[j], s);
#pragma unroll
    for (int o = 32; o > 0; o >>= 1) s += __shfl_down(s, o, 64);
    if (lane == 0) cbuf[0] = s;
    return;
  }
  float su = 0.f, sw = 0.f;
  for (int j = lane; j < NHID; j += 64) {
    su = fmaf(Qw[(size_t)k * NHID + j], Kb[j], su);
    sw = fmaf(Kw[(size_t)k * NHID + j], Qb[j], sw);
  }
#pragma unroll
  for (int o = 32; o > 0; o >>= 1) { su += __shfl_down(su, o, 64); sw += __shfl_down(sw, o, 64); }
  if (lane == 0) { u[k] = su; w[k] = sw; }
}

// ---------------- fused SpMM: h = relu(adj @ xW + b1) + split + a/b dots ----------------
__global__ __launch_bounds__(128) void spmm_fused(const float* __restrict__ xW,
                                                  const int* __restrict__ colidx,
                                                  const int* __restrict__ deg,
                                                  const float* __restrict__ b1,
                                                  const float* __restrict__ u, const float* __restrict__ w,
                                                  float* __restrict__ h, ushort* __restrict__ Hs,
                                                  float* __restrict__ a_vec, float* __restrict__ b_vec) {
  __shared__ int scols[RCAP];
  __shared__ float ra[2], rb[2];
  int row = blockIdx.x, t = threadIdx.x;
  int d = deg[row];
  for (int i = t; i < d; i += 128) scols[i] = colidx[(size_t)row * RCAP + i];
  __syncthreads();
  float4 acc = make_float4(0.f, 0.f, 0.f, 0.f);
  int e = 0;
  for (; e + 8 <= d; e += 8) {
    float4 v0 = ((const float4*)(xW + (size_t)scols[e + 0] * NHID))[t];
    float4 v1 = ((const float4*)(xW + (size_t)scols[e + 1] * NHID))[t];
    float4 v2 = ((const float4*)(xW + (size_t)scols[e + 2] * NHID))[t];
    float4 v3 = ((const float4*)(xW + (size_t)scols[e + 3] * NHID))[t];
    float4 v4 = ((const float4*)(xW + (size_t)scols[e + 4] * NHID))[t];
    float4 v5 = ((const float4*)(xW + (size_t)scols[e + 5] * NHID))[t];
    float4 v6 = ((const float4*)(xW + (size_t)scols[e + 6] * NHID))[t];
    float4 v7 = ((const float4*)(xW + (size_t)scols[e + 7] * NHID))[t];
    acc.x += ((v0.x + v1.x) + (v2.x + v3.x)) + ((v4.x + v5.x) + (v6.x + v7.x));
    acc.y += ((v0.y + v1.y) + (v2.y + v3.y)) + ((v4.y + v5.y) + (v6.y + v7.y));
    acc.z += ((v0.z + v1.z) + (v2.z + v3.z)) + ((v4.z + v5.z) + (v6.z + v7.z));
    acc.w += ((v0.w + v1.w) + (v2.w + v3.w)) + ((v4.w + v5.w) + (v6.w + v7.w));
  }
  for (; e < d; ++e) {
    float4 v = ((const float4*)(xW + (size_t)scols[e] * NHID))[t];
    acc.x += v.x; acc.y += v.y; acc.z += v.z; acc.w += v.w;
  }
  float4 bv = ((const float4*)b1)[t];
  float4 o = make_float4(fmaxf(acc.x + bv.x, 0.f), fmaxf(acc.y + bv.y, 0.f),
                         fmaxf(acc.z + bv.z, 0.f), fmaxf(acc.w + bv.w, 0.f));
  ((float4*)(h + (size_t)row * NHID))[t] = o;
  ushort4 hi, lo;
  hi.x = f2bf(o.x); hi.y = f2bf(o.y); hi.z = f2bf(o.z); hi.w = f2bf(o.w);
  lo.x = f2bf(o.x - bf2f(hi.x)); lo.y = f2bf(o.y - bf2f(hi.y));
  lo.z = f2bf(o.z - bf2f(hi.z)); lo.w = f2bf(o.w - bf2f(hi.w));
  ushort* hr = Hs + (size_t)row * KA_SPLIT;
  ((ushort4*)hr)[t] = hi;
  ((ushort4*)(hr + 512))[t] = lo;
  float4 uv = ((const float4*)u)[t], wv4 = ((const float4*)w)[t];
  float sa = fmaf(o.x, uv.x, fmaf(o.y, uv.y, fmaf(o.z, uv.z, o.w * uv.w)));
  float sb = fmaf(o.x, wv4.x, fmaf(o.y, wv4.y, fmaf(o.z, wv4.z, o.w * wv4.w)));
  int wv = t >> 6, lane = t & 63;
#pragma unroll
  for (int off = 32; off > 0; off >>= 1) { sa += __shfl_down(sa, off, 64); sb += __shfl_down(sb, off, 64); }
  if (lane == 0) { ra[wv] = sa; rb[wv] = sb; }
  __syncthreads();
  if (t == 0) { a_vec[row] = ra[0] + ra[1]; b_vec[row] = rb[0] + rb[1]; }
}

// ---------------- two-level score pass: bf16 filter -> fp32 rescore of candidates ----------------
// One wave per row (4 rows/block). Phase A: filter scores via bf16 h-hi gather (1 KB/row, half
// the bytes) against EXACT fp32 G held in registers; worst-case filter error ~41 << margin 96.
// Phase B: exact fp32 rescore of candidates only (~1.1/row), closed-form-background softmax,
// thresholded aggregate of candidate Vh rows + background*T, LayerNorm. Exact to < e^-55.
__global__ __launch_bounds__(256) void score2_agg_ln(
    const float* __restrict__ G, int ldg, const float* __restrict__ h,
    const ushort* __restrict__ Hs, const int* __restrict__ colidx, const int* __restrict__ deg,
    const float* __restrict__ a_vec, const float* __restrict__ b_vec,
    const float* __restrict__ cbuf, const float* __restrict__ Vh, int ldv,
    const float* __restrict__ T, const float* __restrict__ lng,
    const float* __restrict__ lnb, float* __restrict__ Xt) {
  __shared__ int scols[4][RCAP];
  __shared__ float sbv[4][RCAP];
  __shared__ float sv[4][RCAP];
  __shared__ int cand[4][CANDCAP];
  __shared__ int ccnt[4];
  int t = threadIdx.x, wv = t >> 6, lane = t & 63;
  int row = blockIdx.x * 4 + wv;
  int d = deg[row];
  int q = lane >> 4, u = lane & 15;
  if (lane == 0) ccnt[wv] = 0;
  // exact fp32 G row -> quarter-wave-replicated registers.
  // ga4[it2][p] = G[128*it2 + 8u + 4p .. +3]
  float4 ga4[4][2];
  const float4* Gr4 = (const float4*)(G + (size_t)row * ldg);
#pragma unroll
  for (int it2 = 0; it2 < 4; ++it2) {
    ga4[it2][0] = Gr4[it2 * 32 + 2 * u];
    ga4[it2][1] = Gr4[it2 * 32 + 2 * u + 1];
  }
  for (int i = lane; i < d; i += 64) {
    int c = colidx[(size_t)row * RCAP + i];
    scols[wv][i] = c;
    sbv[wv][i] = b_vec[c];
  }
  __syncthreads();
  // ---- Phase A: filter scores from bf16 h-hi (1 KB gathers) ----
  for (int e0 = 0; e0 < d; e0 += 4) {
    int e = e0 + q;
    bool act = e < d;
    int col = scols[wv][act ? e : 0];
    const uint4* hr = (const uint4*)(Hs + (size_t)col * KA_SPLIT);  // hi = first 1 KB = 64 uint4
    float s_a = 0.f, s_b = 0.f;
#pragma unroll
    for (int it2 = 0; it2 < 4; ++it2) {
      uint4 p = hr[it2 * 16 + u];
      float4 g0 = ga4[it2][0], g1 = ga4[it2][1];
      s_a = fmaf(__uint_as_float(p.x << 16), g0.x, s_a);
      s_a = fmaf(__uint_as_float(p.x & 0xffff0000u), g0.y, s_a);
      s_a = fmaf(__uint_as_float(p.y << 16), g0.z, s_a);
      s_a = fmaf(__uint_as_float(p.y & 0xffff0000u), g0.w, s_a);
      s_b = fmaf(__uint_as_float(p.z << 16), g1.x, s_b);
      s_b = fmaf(__uint_as_float(p.z & 0xffff0000u), g1.y, s_b);
      s_b = fmaf(__uint_as_float(p.w << 16), g1.z, s_b);
      s_b = fmaf(__uint_as_float(p.w & 0xffff0000u), g1.w, s_b);
    }
    float s = s_a + s_b;
    s += __shfl_down(s, 8, 16);
    s += __shfl_down(s, 4, 16);
    s += __shfl_down(s, 2, 16);
    s += __shfl_down(s, 1, 16);
    if (u == 0 && act) sv[wv][e] = s + sbv[wv][e];  // b_j affects ranking; a_i+c is row-const
  }
  __syncthreads();
  float fm = -1e30f;
  for (int i = lane; i < d; i += 64) fm = fmaxf(fm, sv[wv][i]);
#pragma unroll
  for (int o = 32; o > 0; o >>= 1) fm = fmaxf(fm, __shfl_xor(fm, o, 64));
  // candidate list: edges within FILTER_MARGIN of the row's filter max
  for (int i = lane; i < d; i += 64) {
    if (sv[wv][i] >= fm - FILTER_MARGIN) {
      int p = atomicAdd(&ccnt[wv], 1);
      if (p < CANDCAP) cand[wv][p] = i;
    }
  }
  __syncthreads();
  int nc = ccnt[wv];
  bool ovf = nc > CANDCAP;       // degenerate near-tie row: rescore ALL edges (rare, still exact)
  if (ovf) nc = d;
  float ai = a_vec[row] + cbuf[0];
  // ---- Phase B: exact fp32 rescore of candidates ----
  for (int c0 = 0; c0 < nc; c0 += 4) {
    int idx = c0 + q;
    bool act = idx < nc;
    int e = act ? (ovf ? idx : cand[wv][idx]) : 0;
    int col = scols[wv][e];
    const float4* hr = (const float4*)(h + (size_t)col * NHID);
    float s_a = 0.f, s_b = 0.f;
#pragma unroll
    for (int it2 = 0; it2 < 4; ++it2) {
      float4 h0 = hr[it2 * 32 + 2 * u], h1 = hr[it2 * 32 + 2 * u + 1];
      float4 g0 = ga4[it2][0], g1 = ga4[it2][1];
      s_a = fmaf(h0.x, g0.x, s_a); s_a = fmaf(h0.y, g0.y, s_a);
      s_a = fmaf(h0.z, g0.z, s_a); s_a = fmaf(h0.w, g0.w, s_a);
      s_b = fmaf(h1.x, g1.x, s_b); s_b = fmaf(h1.y, g1.y, s_b);
      s_b = fmaf(h1.z, g1.z, s_b); s_b = fmaf(h1.w, g1.w, s_b);
    }
    float s = s_a + s_b;
    s += __shfl_down(s, 8, 16);
    s += __shfl_down(s, 4, 16);
    s += __shfl_down(s, 2, 16);
    s += __shfl_down(s, 1, 16);
    if (u == 0 && act) sv[wv][e] = s + ai + sbv[wv][e];  // exact score
  }
  __syncthreads();
  // softmax over candidates + implicit background zeros (non-candidates contribute < e^-55)
  float m = 0.f;
  for (int i = lane; i < nc; i += 64) {
    int e = ovf ? i : cand[wv][i];
    m = fmaxf(m, sv[wv][e]);
  }
#pragma unroll
  for (int o = 32; o > 0; o >>= 1) m = fmaxf(m, __shfl_xor(m, o, 64));
  float ssum = 0.f;
  for (int i = lane; i < nc; i += 64) {
    int e = ovf ? i : cand[wv][i];
    float ex = expf(sv[wv][e] - m);
    sv[wv][e] = ex;
    ssum += ex;
  }
#pragma unroll
  for (int o = 32; o > 0; o >>= 1) ssum += __shfl_xor(ssum, o, 64);
  float em = expf(-m);
  float inv = 1.f / (ssum + (float)(N_NODES - d) * em);
  float ci = em * inv;
  __syncthreads();
  // aggregate candidate Vh rows (weight > 1e-12) + background*T, then LayerNorm
  float4 a0 = make_float4(0.f, 0.f, 0.f, 0.f), a1 = a0;
  for (int i = 0; i < nc; ++i) {
    int e = ovf ? i : cand[wv][i];
    float we = sv[wv][e] * inv;
    if (we > 1e-12f) {
      const float4* vr = (const float4*)(Vh + (size_t)scols[wv][e] * ldv);
      float4 v0 = vr[lane * 2], v1 = vr[lane * 2 + 1];
      a0.x = fmaf(we, v0.x, a0.x); a0.y = fmaf(we, v0.y, a0.y);
      a0.z = fmaf(we, v0.z, a0.z); a0.w = fmaf(we, v0.w, a0.w);
      a1.x = fmaf(we, v1.x, a1.x); a1.y = fmaf(we, v1.y, a1.y);
      a1.z = fmaf(we, v1.z, a1.z); a1.w = fmaf(we, v1.w, a1.w);
    }
  }
  float4 t0 = ((const float4*)T)[lane * 2], t1 = ((const float4*)T)[lane * 2 + 1];
  a0.x = fmaf(ci, t0.x, a0.x); a0.y = fmaf(ci, t0.y, a0.y);
  a0.z = fmaf(ci, t0.z, a0.z); a0.w = fmaf(ci, t0.w, a0.w);
  a1.x = fmaf(ci, t1.x, a1.x); a1.y = fmaf(ci, t1.y, a1.y);
  a1.z = fmaf(ci, t1.z, a1.z); a1.w = fmaf(ci, t1.w, a1.w);
  float s1 = ((a0.x + a0.y) + (a0.z + a0.w)) + ((a1.x + a1.y) + (a1.z + a1.w));
  float s2 = ((a0.x * a0.x + a0.y * a0.y) + (a0.z * a0.z + a0.w * a0.w)) +
             ((a1.x * a1.x + a1.y * a1.y) + (a1.z * a1.z + a1.w * a1.w));
#pragma unroll
  for (int o = 32; o > 0; o >>= 1) { s1 += __shfl_xor(s1, o, 64); s2 += __shfl_xor(s2, o, 64); }
  float mu = s1 * (1.f / NHID);
  float var = s2 * (1.f / NHID) - mu * mu;
  float rstd = rsqrtf(var + 1e-5f);
  float4 g0 = ((const float4*)lng)[lane * 2], g1 = ((const float4*)lng)[lane * 2 + 1];
  float4 b0 = ((const float4*)lnb)[lane * 2], b1 = ((const float4*)lnb)[lane * 2 + 1];
  float4 o0, o1;
  o0.x = (a0.x - mu) * rstd * g0.x + b0.x;
  o0.y = (a0.y - mu) * rstd * g0.y + b0.y;
  o0.z = (a0.z - mu) * rstd * g0.z + b0.z;
  o0.w = (a0.w - mu) * rstd * g0.w + b0.w;
  o1.x = (a1.x - mu) * rstd * g1.x + b1.x;
  o1.y = (a1.y - mu) * rstd * g1.y + b1.y;
  o1.z = (a1.z - mu) * rstd * g1.z + b1.z;
  o1.w = (a1.w - mu) * rstd * g1.w + b1.w;
  float4* xr = (float4*)(Xt + (size_t)row * NHID);
  xr[lane * 2] = o0;
  xr[lane * 2 + 1] = o1;
}

// ---------------- Y = Xt @ W2 (512 -> 8), one wave per row ----------------
__global__ __launch_bounds__(256) void xt_w2(const float* __restrict__ Xt, const float* __restrict__ W2,
                                             float* __restrict__ Y) {
  __shared__ float w2s[NHID * NCLASS];
  int t = threadIdx.x;
  for (int i = t; i < NHID * NCLASS; i += 256) w2s[i] = W2[i];
  __syncthreads();
  int wv = t >> 6, lane = t & 63;
  int row = blockIdx.x * 4 + wv;
  const float4* xr = (const float4*)(Xt + (size_t)row * NHID);
  float4 x0 = xr[lane * 2], x1 = xr[lane * 2 + 1];
  float xv[8] = {x0.x, x0.y, x0.z, x0.w, x1.x, x1.y, x1.z, x1.w};
  float acc[NCLASS];
#pragma unroll
  for (int c = 0; c < NCLASS; ++c) acc[c] = 0.f;
#pragma unroll
  for (int kk = 0; kk < 8; ++kk) {
    int k = lane * 8 + kk;
#pragma unroll
    for (int c = 0; c < NCLASS; ++c) acc[c] = fmaf(xv[kk], w2s[k * NCLASS + c], acc[c]);
  }
#pragma unroll
  for (int c = 0; c < NCLASS; ++c)
#pragma unroll
    for (int o = 32; o > 0; o >>= 1) acc[c] += __shfl_down(acc[c], o, 64);
  if (lane == 0) {
    *(float4*)(Y + (size_t)row * NCLASS) = make_float4(acc[0], acc[1], acc[2], acc[3]);
    *(float4*)(Y + (size_t)row * NCLASS + 4) = make_float4(acc[4], acc[5], acc[6], acc[7]);
  }
}

// ---------------- z = adj @ Y + b2, softmax over 8 classes ----------------
__global__ __launch_bounds__(256) void final_spmm_softmax(const float* __restrict__ Y,
                                                          const int* __restrict__ colidx,
                                                          const int* __restrict__ deg,
                                                          const float* __restrict__ b2,
                                                          float* __restrict__ out) {
  int t = threadIdx.x;
  int wv = t >> 6, lane = t & 63;
  int row = blockIdx.x * 4 + wv;
  int d = deg[row];
  const int* cols = colidx + (size_t)row * RCAP;
  float acc[8];
#pragma unroll
  for (int c = 0; c < 8; ++c) acc[c] = 0.f;
  for (int e = lane; e < d; e += 64) {
    int col = cols[e];
    const float4* yr = (const float4*)(Y + (size_t)col * 8);
    float4 y0 = yr[0], y1 = yr[1];
    acc[0] += y0.x; acc[1] += y0.y; acc[2] += y0.z; acc[3] += y0.w;
    acc[4] += y1.x; acc[5] += y1.y; acc[6] += y1.z; acc[7] += y1.w;
  }
#pragma unroll
  for (int c = 0; c < 8; ++c)
#pragma unroll
    for (int o = 32; o > 0; o >>= 1) acc[c] += __shfl_down(acc[c], o, 64);
  if (lane == 0) {
    float z[8];
    float m = -1e30f;
#pragma unroll
    for (int c = 0; c < 8; ++c) { z[c] = acc[c] + b2[c]; m = fmaxf(m, z[c]); }
    float s = 0.f;
#pragma unroll
    for (int c = 0; c < 8; ++c) { z[c] = expf(z[c] - m); s += z[c]; }
    float inv = 1.f / s;
    *(float4*)(out + (size_t)row * 8) = make_float4(z[0] * inv, z[1] * inv, z[2] * inv, z[3] * inv);
    *(float4*)(out + (size_t)row * 8 + 4) = make_float4(z[4] * inv, z[5] * inv, z[6] * inv, z[7] * inv);
  }
}

extern "C" void kernel_launch(void* const* d_in, const int* in_sizes, int n_in,
                              void* d_out, int out_size, void* d_ws, size_t ws_size,
                              hipStream_t stream) {
  const float* adj = (const float*)d_in[0];
  const float* x = (const float*)d_in[1];
  const float* W1 = (const float*)d_in[2];
  const float* b1 = (const float*)d_in[3];
  const float* Qw = (const float*)d_in[4];
  const float* Qb = (const float*)d_in[5];
  const float* Kw = (const float*)d_in[6];
  const float* Kb = (const float*)d_in[7];
  const float* Vw = (const float*)d_in[8];
  const float* Vb = (const float*)d_in[9];
  const float* ln_g = (const float*)d_in[10];
  const float* ln_b = (const float*)d_in[11];
  const float* W2 = (const float*)d_in[12];
  const float* b2 = (const float*)d_in[13];
  float* out = (float*)d_out;

  char* ws = (char*)d_ws;
  size_t off = 0;
  auto alloc = [&](size_t bytes) -> void* {
    void* p = ws + off;
    off = (off + bytes + 255) & ~(size_t)255;
    return p;
  };
  int* colidx = (int*)alloc((size_t)N_NODES * RCAP * 4);
  int* deg = (int*)alloc((size_t)N_NODES * 4);
  float* bufA = (float*)alloc((size_t)N_NODES * NHID * 4);     // xW, then Xt
  float* bufB = (float*)alloc((size_t)N_NODES * NHID * 4);     // h
  float* GVh = (float*)alloc((size_t)N_NODES * 1024 * 4);      // [G | Vh], stride 1024
  ushort* Xs = (ushort*)alloc((size_t)N_NODES * KA_SPLIT * 2); // split x [hi|lo]
  ushort* Hs = (ushort*)alloc((size_t)N_NODES * KA_SPLIT * 2); // split h [hi|lo]
  ushort* W1ts = (ushort*)alloc((size_t)512 * KB_SPLIT * 2);   // split W1^T [hi|lo|hi]
  ushort* Bcts = (ushort*)alloc((size_t)1024 * KB_SPLIT * 2);  // split [M|Vw]^T
  float* KwT = (float*)alloc((size_t)512 * 512 * 4);
  float* Mmat = (float*)alloc((size_t)512 * 512 * 4);
  float* bcat = (float*)alloc((size_t)1024 * 4);
  float* a_vec = (float*)alloc((size_t)N_NODES * 4);
  float* b_vec = (float*)alloc((size_t)N_NODES * 4);
  float* u_vec = (float*)alloc((size_t)NHID * 4);
  float* w_vec = (float*)alloc((size_t)NHID * 4);
  float* cbuf = (float*)alloc(256);
  float* T = (float*)alloc((size_t)NHID * 4);
  float* Y = (float*)alloc((size_t)N_NODES * NCLASS * 4);
  (void)in_sizes; (void)n_in; (void)out_size; (void)ws_size;

  // 1) sparse structure from dense adj
  build_ell<<<N_NODES, 256, 0, stream>>>(adj, colidx, deg);
  // 2) M = Qw@Kw^T (fp32, small); rank-1 bias terms
  transpose512<<<dim3(16, 16), dim3(32, 8), 0, stream>>>(Kw, KwT);
  bias_prep<<<NHID + 1, 64, 0, stream>>>(Qw, Kw, Qb, Kb, u_vec, w_vec, cbuf);
  sgemm64x128<<<dim3(4, 8), 256, 0, stream>>>(Qw, KwT, Mmat, 512, 512, 512, 512);
  // 3) splits; xW = x@W1 via bf16x3 MFMA
  split_a2<<<(N_NODES * 128) / 256, 256, 0, stream>>>(x, Xs);
  split_bt<<<(512 * 384) / 256, 256, 0, stream>>>(W1, W1ts, 512);
  mfma_gemm_bt<<<dim3(4, 64), 256, 0, stream>>>(Xs, W1ts, nullptr, bufA, 512, nullptr);
  // 4) h = relu(adj@xW + b1): fused gather + split + a/b vectors
  spmm_fused<<<N_NODES, 128, 0, stream>>>(bufA, colidx, deg, b1, u_vec, w_vec, bufB, Hs, a_vec, b_vec);
  // 5) [G | Vh] = h @ [M | Vw] (+[0|Vb]) via MFMA, fused T = colsum(Vh)
  split_bt_cat<<<(1024 * 384) / 256, 256, 0, stream>>>(Mmat, Vw, Bcts);
  prep_misc<<<6, 256, 0, stream>>>(Vb, bcat, T);
  mfma_gemm_bt<<<dim3(8, 64), 256, 0, stream>>>(Hs, Bcts, bcat, GVh, 1024, T);
  // 6) two-level scores (bf16 filter + fp32 rescore) + softmax + aggregate + LN -> Xt (bufA)
  score2_agg_ln<<<N_NODES / 4, 256, 0, stream>>>(GVh, 1024, bufB, Hs, colidx, deg, a_vec, b_vec,
                                                 cbuf, GVh + 512, 1024, T, ln_g, ln_b, bufA);
  // 7) Y = Xt @ W2 ; z = adj @ Y + b2 ; softmax
  xt_w2<<<N_NODES / 4, 256, 0, stream>>>(bufA, W2, Y);
  final_spmm_softmax<<<N_NODES / 4, 256, 0, stream>>>(Y, colidx, deg, b2, out);
}